// Round 6
// baseline (419.071 us; speedup 1.0000x reference)
//
#include <hip/hip_runtime.h>

// Problem constants (match reference)
constexpr int NUM_CLASSES  = 100000;
constexpr int EMBED_DIM    = 512;
constexpr int BATCH        = 16384;
constexpr int CENTER_ELEMS = NUM_CLASSES * EMBED_DIM;   // 51,200,000
constexpr int NSLOTS       = 256;                        // loss partial slots
constexpr int KMAX         = 8;                          // per-class item list capacity
constexpr float UPDATE_SCALE = 0.05f;                    // (1 - ALPHA)
constexpr float INV_COUNT  = 1.0f / 8388608.0f;          // 1/(BATCH*EMBED_DIM) = 2^-23

typedef float f4 __attribute__((ext_vector_type(4)));

// ---------------- workspace layout (int units from base) ----------------
// counts[NC] | items[NC*KMAX] | partials[NSLOTS]
constexpr size_t WS_COUNTS_OFF  = 0;
constexpr size_t WS_ITEMS_OFF   = WS_COUNTS_OFF + (size_t)NUM_CLASSES;
constexpr size_t WS_PART_OFF    = WS_ITEMS_OFF + (size_t)NUM_CLASSES * KMAX;
constexpr size_t WS_NEW         = (WS_PART_OFF + NSLOTS) * 4;

__global__ void zero_ws_kernel(int* __restrict__ counts,
                               float* __restrict__ partials) {
    int g = blockIdx.x * blockDim.x + threadIdx.x;
    if (g < NUM_CLASSES) counts[g] = 0;
    if (g < NSLOTS) partials[g] = 0.0f;
}

// histogram + per-class item list (first KMAX items recorded exactly)
__global__ void hist_kernel(const int* __restrict__ labels,
                            int* __restrict__ counts,
                            int* __restrict__ items) {
    int b = blockIdx.x * blockDim.x + threadIdx.x;
    if (b < BATCH) {
        int l = labels[b];
        int r = atomicAdd(&counts[l], 1);
        if (r < KMAX) items[l * KMAX + r] = b;
    }
}

// One 64-lane wave per class row, grid-strided. Lane l holds f4 slots 2l,2l+1
// of the row (8 floats). Untouched rows: pure register copy. Touched rows:
// exact deterministic <=KMAX update + loss partial. Output new_centers lives
// at out+1 (4B misaligned): the shift is done in-register with one shfl_up —
//   out-slot 2l   = {prev-lane n1.w, n0.x, n0.y, n0.z}
//   out-slot 2l+1 = {n0.w, n1.x, n1.y, n1.z}
// out[c*512] (last elem of row c-1) is written by row c-1's lane 63 as
// out[base+512]; row c's lane 0 skips its slot-0 .x and stores out[base+1..3]
// scalar. All f4 accesses aligned; no LDS; no syncthreads; no races.
__global__ __launch_bounds__(256) void fused_stream_kernel(
        const float* __restrict__ features,
        const float* __restrict__ centers,
        const int*   __restrict__ labels,
        const int*   __restrict__ counts,
        const int*   __restrict__ items,
        float* __restrict__ out,            // out[0]=loss, out+1 = new_centers
        float* __restrict__ partials) {
    const int lane   = threadIdx.x & 63;
    const int gwave  = blockIdx.x * (blockDim.x >> 6) + (threadIdx.x >> 6);
    const int nwaves = gridDim.x * (blockDim.x >> 6);

    for (int c = gwave; c < NUM_CLASSES; c += nwaves) {
        const size_t base = (size_t)c * EMBED_DIM;
        const f4* crow = (const f4*)(centers + base);
        const f4 v0 = crow[2 * lane];
        const f4 v1 = crow[2 * lane + 1];
        const int cnt = counts[c];

        f4 n0 = v0, n1 = v1;
        if (cnt > 0) {
            f4 s0, s1;
            s0.x = s0.y = s0.z = s0.w = 0.0f;
            s1.x = s1.y = s1.z = s1.w = 0.0f;
            float local = 0.0f;
            if (cnt <= KMAX) {
                for (int i = 0; i < cnt; ++i) {
                    const int b = items[c * KMAX + i];
                    const f4* frow = (const f4*)(features + (size_t)b * EMBED_DIM);
                    const f4 f0 = frow[2 * lane];
                    const f4 f1 = frow[2 * lane + 1];
                    float d0x = f0.x - v0.x, d0y = f0.y - v0.y;
                    float d0z = f0.z - v0.z, d0w = f0.w - v0.w;
                    float d1x = f1.x - v1.x, d1y = f1.y - v1.y;
                    float d1z = f1.z - v1.z, d1w = f1.w - v1.w;
                    s0.x += d0x; s0.y += d0y; s0.z += d0z; s0.w += d0w;
                    s1.x += d1x; s1.y += d1y; s1.z += d1z; s1.w += d1w;
                    local += d0x * d0x + d0y * d0y + d0z * d0z + d0w * d0w
                           + d1x * d1x + d1y * d1y + d1z * d1z + d1w * d1w;
                }
            } else {
                // correctness net, P ~ 2e-8 for this data
                for (int b = 0; b < BATCH; ++b) {
                    if (labels[b] == c) {
                        const f4* frow = (const f4*)(features + (size_t)b * EMBED_DIM);
                        const f4 f0 = frow[2 * lane];
                        const f4 f1 = frow[2 * lane + 1];
                        float d0x = f0.x - v0.x, d0y = f0.y - v0.y;
                        float d0z = f0.z - v0.z, d0w = f0.w - v0.w;
                        float d1x = f1.x - v1.x, d1y = f1.y - v1.y;
                        float d1z = f1.z - v1.z, d1w = f1.w - v1.w;
                        s0.x += d0x; s0.y += d0y; s0.z += d0z; s0.w += d0w;
                        s1.x += d1x; s1.y += d1y; s1.z += d1z; s1.w += d1w;
                        local += d0x * d0x + d0y * d0y + d0z * d0z + d0w * d0w
                               + d1x * d1x + d1y * d1y + d1z * d1z + d1w * d1w;
                    }
                }
            }
            n0.x = fmaf(UPDATE_SCALE, s0.x, v0.x);
            n0.y = fmaf(UPDATE_SCALE, s0.y, v0.y);
            n0.z = fmaf(UPDATE_SCALE, s0.z, v0.z);
            n0.w = fmaf(UPDATE_SCALE, s0.w, v0.w);
            n1.x = fmaf(UPDATE_SCALE, s1.x, v1.x);
            n1.y = fmaf(UPDATE_SCALE, s1.y, v1.y);
            n1.z = fmaf(UPDATE_SCALE, s1.z, v1.z);
            n1.w = fmaf(UPDATE_SCALE, s1.w, v1.w);
            #pragma unroll
            for (int off = 32; off > 0; off >>= 1)
                local += __shfl_down(local, off, 64);
            if (lane == 0)
                atomicAdd(&partials[c & (NSLOTS - 1)], local);
        }

        // shifted store (out+1 alignment handled in-register)
        const float prevw = __shfl_up(n1.w, 1, 64);  // lane l-1's n1.w
        f4 o0, o1;
        o0.x = prevw; o0.y = n0.x; o0.z = n0.y; o0.w = n0.z;
        o1.x = n0.w;  o1.y = n1.x; o1.z = n1.y; o1.w = n1.z;
        f4* obase = (f4*)out + (size_t)c * (EMBED_DIM / 4);
        if (lane > 0) {
            obase[2 * lane] = o0;
        } else {
            out[base + 1] = n0.x;
            out[base + 2] = n0.y;
            out[base + 3] = n0.z;
        }
        obase[2 * lane + 1] = o1;
        if (lane == 63)
            out[base + EMBED_DIM] = n1.w;
    }
}

__global__ __launch_bounds__(64) void finalize_loss_kernel(
        const float* __restrict__ partials,
        float* __restrict__ out) {
    float v = 0.0f;
    #pragma unroll
    for (int k = 0; k < NSLOTS / 64; ++k)
        v += partials[threadIdx.x + k * 64];
    #pragma unroll
    for (int off = 32; off > 0; off >>= 1)
        v += __shfl_down(v, off, 64);
    if (threadIdx.x == 0)
        out[0] = v * INV_COUNT;
}

// ---------------- fallback path (proven correct, tiny ws) ----------------

__global__ void copy_centers_kernel(const float* __restrict__ src,
                                    float* __restrict__ dst,
                                    float* __restrict__ ws_partials) {
    int gid = blockIdx.x * blockDim.x + threadIdx.x;
    if (gid < NSLOTS) ws_partials[gid] = 0.0f;
    int stride = gridDim.x * blockDim.x;
    for (int i = gid; i < CENTER_ELEMS; i += stride) dst[i] = src[i];
}

__global__ __launch_bounds__(128) void update_kernel(
        const float* __restrict__ features,
        const int*   __restrict__ labels,
        const float* __restrict__ centers,
        float* __restrict__ out,
        float* __restrict__ ws_partials) {
    const int b = blockIdx.x;
    const int label = labels[b];
    const int t = threadIdx.x;
    const float4 f = ((const float4*)(features + (size_t)b * EMBED_DIM))[t];
    const float4 c = ((const float4*)(centers + (size_t)label * EMBED_DIM))[t];
    float4 d;
    d.x = f.x - c.x; d.y = f.y - c.y; d.z = f.z - c.z; d.w = f.w - c.w;
    float* nrow = out + 1 + (size_t)label * EMBED_DIM + (size_t)t * 4;
    atomicAdd(nrow + 0, UPDATE_SCALE * d.x);
    atomicAdd(nrow + 1, UPDATE_SCALE * d.y);
    atomicAdd(nrow + 2, UPDATE_SCALE * d.z);
    atomicAdd(nrow + 3, UPDATE_SCALE * d.w);
    float local = d.x * d.x + d.y * d.y + d.z * d.z + d.w * d.w;
    #pragma unroll
    for (int off = 32; off > 0; off >>= 1)
        local += __shfl_down(local, off, 64);
    if ((t & 63) == 0)
        atomicAdd(&ws_partials[(b * 2 + (t >> 6)) & (NSLOTS - 1)], local);
}

// ---------------- launcher ----------------

extern "C" void kernel_launch(void* const* d_in, const int* in_sizes, int n_in,
                              void* d_out, int out_size, void* d_ws, size_t ws_size,
                              hipStream_t stream) {
    const float* features = (const float*)d_in[0];
    const int*   labels   = (const int*)d_in[1];
    const float* centers  = (const float*)d_in[2];
    float* out = (float*)d_out;

    if (ws_size >= WS_NEW) {
        int* wsi        = (int*)d_ws;
        int* counts     = wsi + WS_COUNTS_OFF;
        int* items      = wsi + WS_ITEMS_OFF;
        float* partials = (float*)(wsi + WS_PART_OFF);

        zero_ws_kernel<<<(NUM_CLASSES + 255) / 256, 256, 0, stream>>>(
            counts, partials);
        hist_kernel<<<(BATCH + 255) / 256, 256, 0, stream>>>(
            labels, counts, items);
        fused_stream_kernel<<<2048, 256, 0, stream>>>(
            features, centers, labels, counts, items, out, partials);
        finalize_loss_kernel<<<1, 64, 0, stream>>>(partials, out);
    } else {
        float* partials = (float*)d_ws;
        copy_centers_kernel<<<8192, 256, 0, stream>>>(centers, out + 1, partials);
        update_kernel<<<BATCH, 128, 0, stream>>>(features, labels, centers, out, partials);
        finalize_loss_kernel<<<1, 64, 0, stream>>>(partials, out);
    }
}